// Round 5
// baseline (468.803 us; speedup 1.0000x reference)
//
#include <hip/hip_runtime.h>
#include <hip/hip_bf16.h>
#include <math.h>

// Problem constants (from reference)
#define VDIM 50000   // K (vocab / nodeNum)
#define BDIM 1024    // M (batch)
#define EDIM 256     // N (embedding)
#define LDIM 17      // Huffman path length

constexpr int BM = 128, BN = 128, BK = 32;
constexpr int KT_FULL = VDIM / BK;            // 1562 full k-tiles
constexpr int SPLITS  = 64;                   // interleaved split-K -> grid 1024
constexpr int TAILZ   = KT_FULL % SPLITS;     // 26: split owning the 16-col tail tile

typedef short bf16x8 __attribute__((ext_vector_type(8)));  // 8 bf16 (4 VGPRs)
typedef float f32x4  __attribute__((ext_vector_type(4)));

// 8 consecutive fp32 -> bf16 hi fragment + bf16 lo fragment.
// hi = truncate(f); lo = truncate(f - hi); total representation error <= 2^-16 |f|.
__device__ __forceinline__ void split8(const float4 f0, const float4 f1, bf16x8& h, bf16x8& l) {
    const float f[8] = {f0.x, f0.y, f0.z, f0.w, f1.x, f1.y, f1.z, f1.w};
#pragma unroll
    for (int i = 0; i < 8; ++i) {
        const uint32_t u  = __float_as_uint(f[i]);
        h[i] = (short)(u >> 16);
        const float lo = f[i] - __uint_as_float(u & 0xFFFF0000u);
        l[i] = (short)(__float_as_uint(lo) >> 16);
    }
}

// emb_partial = x @ W^T via split-K atomics; bf16 split-3 (Ah*Bh + Ah*Bl + Al*Bh).
// K-loop is LDS-free and barrier-free: each lane loads its MFMA fragment bytes
// (8 contiguous fp32 per operand row) straight from global into registers.
// Every wave is an independent load->convert->MFMA pipeline; latency is hidden
// by wave-level TLP (no block-wide vmcnt(0) drain anywhere in the loop).
__global__ __launch_bounds__(256) void gemm_split3(
    const float* __restrict__ X, const float* __restrict__ Wm, float* __restrict__ emb) {
    const int tid = threadIdx.x;
    const int z   = blockIdx.x;               // split index (fastest -> k-streams spread over XCDs;
                                              //  the 2 bn-blocks of a panel sit 512 apart -> same XCD)
    const int bm0 = blockIdx.y * BM;          // B offset
    const int bn0 = blockIdx.z * BN;          // E offset

    const int lane = tid & 63;
    const int wv   = tid >> 6;                // wave 0..3
    const int wm0  = (wv >> 1) * 64;          // wave tile origin
    const int wn0  = (wv & 1) * 64;
    const int lm   = lane & 15;               // fragment m/n index
    const int kg   = lane >> 4;               // k-quad: fragment covers k = kg*8 .. kg*8+7

    size_t rowA[4], rowB[4];
#pragma unroll
    for (int i = 0; i < 4; ++i) {
        rowA[i] = (size_t)(bm0 + wm0 + i * 16 + lm) * VDIM;
        rowB[i] = (size_t)(bn0 + wn0 + i * 16 + lm) * VDIM;
    }

    f32x4 acc[4][4] = {};

    auto do_tile = [&](const float4 a[4][2], const float4 b[4][2]) {
        bf16x8 ah[4], al[4], bh[4], bl[4];
#pragma unroll
        for (int i = 0; i < 4; ++i) split8(a[i][0], a[i][1], ah[i], al[i]);
#pragma unroll
        for (int i = 0; i < 4; ++i) split8(b[i][0], b[i][1], bh[i], bl[i]);
#pragma unroll
        for (int mi = 0; mi < 4; ++mi)
#pragma unroll
            for (int ni = 0; ni < 4; ++ni) {
                acc[mi][ni] = __builtin_amdgcn_mfma_f32_16x16x32_bf16(ah[mi], bh[ni], acc[mi][ni], 0, 0, 0);
                acc[mi][ni] = __builtin_amdgcn_mfma_f32_16x16x32_bf16(ah[mi], bl[ni], acc[mi][ni], 0, 0, 0);
                acc[mi][ni] = __builtin_amdgcn_mfma_f32_16x16x32_bf16(al[mi], bh[ni], acc[mi][ni], 0, 0, 0);
            }
    };

    for (int kt = z; kt < KT_FULL; kt += SPLITS) {
        const size_t k0 = (size_t)kt * BK + kg * 8;   // 16B-aligned: row*200000 + kt*128 + kg*32 bytes
        float4 a[4][2], b[4][2];
#pragma unroll
        for (int i = 0; i < 4; ++i) {
            const float* pa = X + rowA[i] + k0;
            a[i][0] = *reinterpret_cast<const float4*>(pa);
            a[i][1] = *reinterpret_cast<const float4*>(pa + 4);
        }
#pragma unroll
        for (int i = 0; i < 4; ++i) {
            const float* pb = Wm + rowB[i] + k0;
            b[i][0] = *reinterpret_cast<const float4*>(pb);
            b[i][1] = *reinterpret_cast<const float4*>(pb + 4);
        }
        do_tile(a, b);
    }

    if (z == TAILZ) {                         // tail tile kt=1562: cols 49984..49999 valid
        const size_t k0 = (size_t)KT_FULL * BK + kg * 8;
        const float4 zf = make_float4(0.f, 0.f, 0.f, 0.f);
        float4 a[4][2], b[4][2];
#pragma unroll
        for (int i = 0; i < 4; ++i) {
            a[i][0] = a[i][1] = zf;
            b[i][0] = b[i][1] = zf;
            if (kg < 2) {                     // kg 0,1 cover k 49984..49999; kg 2,3 out of range
                const float* pa = X + rowA[i] + k0;
                const float* pb = Wm + rowB[i] + k0;
                a[i][0] = *reinterpret_cast<const float4*>(pa);
                a[i][1] = *reinterpret_cast<const float4*>(pa + 4);
                b[i][0] = *reinterpret_cast<const float4*>(pb);
                b[i][1] = *reinterpret_cast<const float4*>(pb + 4);
            }
        }
        do_tile(a, b);                        // zero-padded k contributes 0
    }

    // epilogue: C/D layout col = lane&15, row = (lane>>4)*4 + reg  [m89/m91-verified]
    const int orow = (lane >> 4) * 4;
#pragma unroll
    for (int mi = 0; mi < 4; ++mi)
#pragma unroll
        for (int ni = 0; ni < 4; ++ni)
#pragma unroll
            for (int r = 0; r < 4; ++r) {
                const int gm = bm0 + wm0 + mi * 16 + orow + r;
                const int gn = bn0 + wn0 + ni * 16 + lm;
                atomicAdd(&emb[gm * EDIM + gn], acc[mi][ni][r]);
            }
}

// Stage 2: per batch row b, out[b] = prod_l sigmoid( sign_l * <pv[b,l,:], emb[b,:]+bias> )
__global__ __launch_bounds__(256) void stage2_kernel(
    const float* __restrict__ emb, const float* __restrict__ bias,
    const float* __restrict__ pv, const int* __restrict__ signs,
    float* __restrict__ out) {
    const int b = blockIdx.x;
    __shared__ float se[EDIM];
    __shared__ float wp[4];
    const int t = threadIdx.x;
    se[t] = emb[b * EDIM + t] + bias[t];
    __syncthreads();
    const int w = t >> 6, lane = t & 63;
    float p = 1.0f;
    for (int l = w; l < LDIM; l += 4) {
        const float4 a = *reinterpret_cast<const float4*>(&pv[((size_t)b * LDIM + l) * EDIM + lane * 4]);
        const float4 e = *reinterpret_cast<const float4*>(&se[lane * 4]);
        float d = a.x * e.x + a.y * e.y + a.z * e.z + a.w * e.w;
#pragma unroll
        for (int off = 32; off > 0; off >>= 1) d += __shfl_xor(d, off, 64);
        const float zz = signs[b * LDIM + l] ? d : -d;
        p *= 1.0f / (1.0f + expf(-zz));
    }
    if (lane == 0) wp[w] = p;
    __syncthreads();
    if (t == 0) out[b] = wp[0] * wp[1] * wp[2] * wp[3];
}

extern "C" void kernel_launch(void* const* d_in, const int* in_sizes, int n_in,
                              void* d_out, int out_size, void* d_ws, size_t ws_size,
                              hipStream_t stream) {
    const float* X    = (const float*)d_in[0];   // [B, V]
    const float* Wm   = (const float*)d_in[1];   // [E, V]
    const float* bias = (const float*)d_in[2];   // [E]
    const float* pv   = (const float*)d_in[3];   // [B, L, E]
    const int*   sg   = (const int*)d_in[4];     // [B, L]
    float* out = (float*)d_out;                  // [B]
    float* emb = (float*)d_ws;                   // [B, E] fp32 accumulator (1 MB)

    hipMemsetAsync(emb, 0, (size_t)BDIM * EDIM * sizeof(float), stream);

    dim3 grid(SPLITS, BDIM / BM, EDIM / BN);     // 64 x 8 x 2 = 1024 blocks
    gemm_split3<<<grid, 256, 0, stream>>>(X, Wm, emb);

    stage2_kernel<<<BDIM, 256, 0, stream>>>(emb, bias, pv, sg, out);
}

// Round 6
// 467.915 us; speedup vs baseline: 1.0019x; 1.0019x over previous
//
#include <hip/hip_runtime.h>
#include <hip/hip_bf16.h>
#include <math.h>

// Problem constants (from reference)
#define VDIM 50000   // K (vocab / nodeNum)
#define BDIM 1024    // M (batch)
#define EDIM 256     // N (embedding)
#define LDIM 17      // Huffman path length

constexpr int BM = 128, BN = 128, BK = 32;
constexpr int LDK = 32;                       // bf16 elements per LDS row (64 B stride)
constexpr int SPLITS = 32;                    // interleaved split-K -> grid 512 = 2 blocks/CU
constexpr int ITERS  = 49;                    // ceil(1563/32); uniform via per-load guards

typedef short bf16x8 __attribute__((ext_vector_type(8)));  // 8 bf16 (4 VGPRs)
typedef float f32x4  __attribute__((ext_vector_type(4)));

// Split one float4 into packed bf16 hi (2x uint32) and bf16 lo (2x uint32).
// hi = truncate(v); lo = truncate(v - hi); total representation error <= 2^-16 |v|.
__device__ __forceinline__ void split4(const float4 v, uint32_t hi[2], uint32_t lo[2]) {
    const uint32_t ux = __float_as_uint(v.x), uy = __float_as_uint(v.y),
                   uz = __float_as_uint(v.z), uw = __float_as_uint(v.w);
    const uint32_t hx = ux & 0xFFFF0000u, hy = uy & 0xFFFF0000u,
                   hz = uz & 0xFFFF0000u, hw = uw & 0xFFFF0000u;
    const float lx = v.x - __uint_as_float(hx);
    const float ly = v.y - __uint_as_float(hy);
    const float lz = v.z - __uint_as_float(hz);
    const float lw = v.w - __uint_as_float(hw);
    hi[0] = (hx >> 16) | hy;
    hi[1] = (hz >> 16) | hw;
    lo[0] = (__float_as_uint(lx) >> 16) | (__float_as_uint(ly) & 0xFFFF0000u);
    lo[1] = (__float_as_uint(lz) >> 16) | (__float_as_uint(lw) & 0xFFFF0000u);
}

struct Buf {            // one k-tile, pre-split: 4 x 8 KB = 32 KB
    ushort Ah[BM * LDK];
    ushort Al[BM * LDK];
    ushort Bh[BN * LDK];
    ushort Bl[BN * LDK];
};

// emb_partial = x @ W^T via split-K atomics; bf16 split-3 (Ah*Bh + Ah*Bl + Al*Bh).
// Double-buffered with TWO DISTINCT __shared__ objects + pair-unrolled loop so the
// compiler can prove stage(buf1) doesn't alias compute(buf0) and keep the staging
// loads in flight across the MFMA block. Split happens once per element at staging;
// the compute phase is pure ds_read_b128 -> MFMA.
__global__ __launch_bounds__(256) void gemm_split3(
    const float* __restrict__ X, const float* __restrict__ Wm, float* __restrict__ emb) {
    __shared__ __align__(16) Buf b0;          // 32 KB
    __shared__ __align__(16) Buf b1;          // 32 KB

    const int tid = threadIdx.x;
    const int bn0 = blockIdx.x * BN;          // E offset
    const int bm0 = blockIdx.y * BM;          // B offset
    const int z   = blockIdx.z;               // split: tiles z, z+SPLITS, ...

    const int lane = tid & 63;
    const int wv   = tid >> 6;                // wave 0..3
    const int wm0  = (wv >> 1) * 64;          // wave tile origin
    const int wn0  = (wv & 1) * 64;
    const int lm   = lane & 15;               // fragment m/n index
    const int lk   = (lane >> 4) * 8;         // fragment k-offset (8 bf16)

    // staging map: thread covers rows sr+32p (p=0..3), k-cols sc..sc+3
    const int sr = tid >> 3;                  // 0..31
    const int sc = (tid & 7) * 4;             // 0,4,...,28

    f32x4 acc[4][4] = {};

    float4 va[4], vb[4];                      // staged fp32 (held across compute)

    auto loadT = [&](int kt) {
        const int gk = kt * BK + sc;
        const bool ok = gk < VDIM;            // VDIM%4==0 -> float4 all-or-nothing
        const int gko = ok ? gk : 0;          // clamp addr; value masked below
        const float4 zf = make_float4(0.f, 0.f, 0.f, 0.f);
#pragma unroll
        for (int p = 0; p < 4; ++p) {
            const int r = sr + p * 32;
            float4 ta = *reinterpret_cast<const float4*>(X  + (size_t)(bm0 + r) * VDIM + gko);
            float4 tb = *reinterpret_cast<const float4*>(Wm + (size_t)(bn0 + r) * VDIM + gko);
            va[p] = ok ? ta : zf;
            vb[p] = ok ? tb : zf;
        }
    };

    auto stageT = [&](Buf& b) {
#pragma unroll
        for (int p = 0; p < 4; ++p) {
            const int r = sr + p * 32;
            uint32_t hi[2], lo[2];
            split4(va[p], hi, lo);
            *reinterpret_cast<uint2*>(&b.Ah[r * LDK + sc]) = make_uint2(hi[0], hi[1]);
            *reinterpret_cast<uint2*>(&b.Al[r * LDK + sc]) = make_uint2(lo[0], lo[1]);
            split4(vb[p], hi, lo);
            *reinterpret_cast<uint2*>(&b.Bh[r * LDK + sc]) = make_uint2(hi[0], hi[1]);
            *reinterpret_cast<uint2*>(&b.Bl[r * LDK + sc]) = make_uint2(lo[0], lo[1]);
        }
    };

    auto compute = [&](const Buf& b) {
        bf16x8 ah[4], al[4], bh[4], bl[4];
#pragma unroll
        for (int mi = 0; mi < 4; ++mi) {
            const int row = wm0 + mi * 16 + lm;
            ah[mi] = *reinterpret_cast<const bf16x8*>(&b.Ah[row * LDK + lk]);
            al[mi] = *reinterpret_cast<const bf16x8*>(&b.Al[row * LDK + lk]);
        }
#pragma unroll
        for (int ni = 0; ni < 4; ++ni) {
            const int row = wn0 + ni * 16 + lm;
            bh[ni] = *reinterpret_cast<const bf16x8*>(&b.Bh[row * LDK + lk]);
            bl[ni] = *reinterpret_cast<const bf16x8*>(&b.Bl[row * LDK + lk]);
        }
#pragma unroll
        for (int mi = 0; mi < 4; ++mi)
#pragma unroll
            for (int ni = 0; ni < 4; ++ni) {
                acc[mi][ni] = __builtin_amdgcn_mfma_f32_16x16x32_bf16(ah[mi], bh[ni], acc[mi][ni], 0, 0, 0);
                acc[mi][ni] = __builtin_amdgcn_mfma_f32_16x16x32_bf16(ah[mi], bl[ni], acc[mi][ni], 0, 0, 0);
                acc[mi][ni] = __builtin_amdgcn_mfma_f32_16x16x32_bf16(al[mi], bh[ni], acc[mi][ni], 0, 0, 0);
            }
    };

    // Pipeline over ITERS=49 logical tiles (idx i -> kt = z + i*SPLITS; guards
    // zero-fill past VDIM, covering the partial tail tile and overshoot alike).
    loadT(z);
    stageT(b0);
    int kt = z + SPLITS;
#pragma unroll 1
    for (int i = 0; i < (ITERS - 1) / 2; ++i, kt += 2 * SPLITS) {
        __syncthreads();                      // b0 writes visible; b1 free (read pre-barrier)
        loadT(kt);                            // loads in flight across compute(b0)
        compute(b0);
        stageT(b1);
        __syncthreads();
        loadT(kt + SPLITS);
        compute(b1);
        stageT(b0);
    }
    __syncthreads();
    compute(b0);                              // tile idx 48

    // epilogue: C/D layout col = lane&15, row = (lane>>4)*4 + reg  [m89/m91-verified]
    const int orow = (lane >> 4) * 4;
#pragma unroll
    for (int mi = 0; mi < 4; ++mi)
#pragma unroll
        for (int ni = 0; ni < 4; ++ni)
#pragma unroll
            for (int r = 0; r < 4; ++r) {
                const int gm = bm0 + wm0 + mi * 16 + orow + r;
                const int gn = bn0 + wn0 + ni * 16 + lm;
                atomicAdd(&emb[gm * EDIM + gn], acc[mi][ni][r]);
            }
}

// Stage 2: per batch row b, out[b] = prod_l sigmoid( sign_l * <pv[b,l,:], emb[b,:]+bias> )
__global__ __launch_bounds__(256) void stage2_kernel(
    const float* __restrict__ emb, const float* __restrict__ bias,
    const float* __restrict__ pv, const int* __restrict__ signs,
    float* __restrict__ out) {
    const int b = blockIdx.x;
    __shared__ float se[EDIM];
    __shared__ float wp[4];
    const int t = threadIdx.x;
    se[t] = emb[b * EDIM + t] + bias[t];
    __syncthreads();
    const int w = t >> 6, lane = t & 63;
    float p = 1.0f;
    for (int l = w; l < LDIM; l += 4) {
        const float4 a = *reinterpret_cast<const float4*>(&pv[((size_t)b * LDIM + l) * EDIM + lane * 4]);
        const float4 e = *reinterpret_cast<const float4*>(&se[lane * 4]);
        float d = a.x * e.x + a.y * e.y + a.z * e.z + a.w * e.w;
#pragma unroll
        for (int off = 32; off > 0; off >>= 1) d += __shfl_xor(d, off, 64);
        const float zz = signs[b * LDIM + l] ? d : -d;
        p *= 1.0f / (1.0f + expf(-zz));
    }
    if (lane == 0) wp[w] = p;
    __syncthreads();
    if (t == 0) out[b] = wp[0] * wp[1] * wp[2] * wp[3];
}

extern "C" void kernel_launch(void* const* d_in, const int* in_sizes, int n_in,
                              void* d_out, int out_size, void* d_ws, size_t ws_size,
                              hipStream_t stream) {
    const float* X    = (const float*)d_in[0];   // [B, V]
    const float* Wm   = (const float*)d_in[1];   // [E, V]
    const float* bias = (const float*)d_in[2];   // [E]
    const float* pv   = (const float*)d_in[3];   // [B, L, E]
    const int*   sg   = (const int*)d_in[4];     // [B, L]
    float* out = (float*)d_out;                  // [B]
    float* emb = (float*)d_ws;                   // [B, E] fp32 accumulator (1 MB)

    hipMemsetAsync(emb, 0, (size_t)BDIM * EDIM * sizeof(float), stream);

    dim3 grid(EDIM / BN, BDIM / BM, SPLITS);     // 2 x 8 x 32 = 512 blocks
    gemm_split3<<<grid, 256, 0, stream>>>(X, Wm, emb);

    stage2_kernel<<<BDIM, 256, 0, stream>>>(emb, bias, pv, sg, out);
}